// Round 1
// baseline (198.022 us; speedup 1.0000x reference)
//
#include <hip/hip_runtime.h>
#include <math.h>

// Problem constants (match reference)
constexpr int C  = 6;
constexpr int NR = 2048;
constexpr int NC = 2048;
constexpr int KS = 10;
constexpr int PAD = 4;            // top/left circular halo (=_PAD_T=_PAD_L)

// Tiling
constexpr int TX = 64;            // output tile cols
constexpr int TY = 64;            // output tile rows
constexpr int RAW_W = TX + KS - 1;   // 73
constexpr int RAW_H = TY + KS - 1;   // 73
constexpr int RAW_STRIDE = 77;       // odd stride -> worst 2-way LDS bank aliasing (free)

__device__ const double MTFd[C] = {0.38, 0.34, 0.34, 0.26, 0.22, 0.23};

__global__ __launch_bounds__(256)
void s2_gaussian_blur_kernel(const float* __restrict__ x, float* __restrict__ out)
{
    __shared__ float  raw[RAW_H * RAW_STRIDE];   // input tile + halo
    __shared__ float  Ht[RAW_H * TX];            // after horizontal pass
    __shared__ double gd[KS];                    // unnormalized 1D gaussian

    const int tid = threadIdx.x;
    const int c   = blockIdx.z;
    const int i0  = blockIdx.y * TY;
    const int j0  = blockIdx.x * TX;

    const float* xc = x   + (size_t)c * NR * NC;
    float*       oc = out + (size_t)c * NR * NC;

    // ---- per-block 1D gaussian weights (double, matches numpy reference) ----
    if (tid < KS) {
        double mtf   = MTFd[c];
        double sigma = 2.0 * sqrt(-2.0 * log(mtf) / (3.14159265358979323846 * 3.14159265358979323846));
        double cd    = -4.5 + (double)tid;
        gd[tid] = exp(-cd * cd / (2.0 * sigma * sigma));
    }

    // ---- load raw tile (wrap addressing; NR,NC are pow2) ----
    for (int idx = tid; idx < RAW_H * RAW_W; idx += 256) {
        int r  = idx / RAW_W;
        int cc = idx - r * RAW_W;
        int gr = (i0 + r  + NR - PAD) & (NR - 1);
        int gc = (j0 + cc + NC - PAD) & (NC - 1);
        raw[r * RAW_STRIDE + cc] = xc[(size_t)gr * NC + gc];
    }
    __syncthreads();

    // ---- normalize weights into registers ----
    float w[KS];
    {
        double s = 0.0;
        #pragma unroll
        for (int d = 0; d < KS; ++d) s += gd[d];
        double inv = 1.0 / s;
        #pragma unroll
        for (int d = 0; d < KS; ++d) w[d] = (float)(gd[d] * inv);
    }

    // ---- horizontal pass: H[r][jj] = sum_d w[d] * raw[r][jj+d] ----
    // items: RAW_H rows x (TX/8)=8 col-groups of 8 outputs; sliding 17-wide window
    for (int item = tid; item < RAW_H * (TX / 8); item += 256) {
        int r = item >> 3;          // / (TX/8)
        int g = item & 7;
        int base = r * RAW_STRIDE + g * 8;
        float v[17];
        #pragma unroll
        for (int k = 0; k < 17; ++k) v[k] = raw[base + k];
        #pragma unroll
        for (int o = 0; o < 8; ++o) {
            float acc = 0.f;
            #pragma unroll
            for (int d = 0; d < KS; ++d) acc = fmaf(w[d], v[o + d], acc);
            Ht[r * TX + g * 8 + o] = acc;
        }
    }
    __syncthreads();

    // ---- vertical pass: out[ii][jj] = sum_d w[d] * H[ii+d][jj] ----
    // thread: fixed jj (lane-contiguous -> conflict-free column reads, coalesced stores),
    // 8-row groups with sliding 17-tall window
    const int jj  = tid & 63;
    const int rg0 = tid >> 6;       // 0..3
    for (int rg = rg0; rg < TY / 8; rg += 4) {
        int base = rg * 8 * TX + jj;
        float v[17];
        #pragma unroll
        for (int k = 0; k < 17; ++k) v[k] = Ht[base + k * TX];
        #pragma unroll
        for (int o = 0; o < 8; ++o) {
            float acc = 0.f;
            #pragma unroll
            for (int d = 0; d < KS; ++d) acc = fmaf(w[d], v[o + d], acc);
            oc[(size_t)(i0 + rg * 8 + o) * NC + (j0 + jj)] = acc;
        }
    }
}

extern "C" void kernel_launch(void* const* d_in, const int* in_sizes, int n_in,
                              void* d_out, int out_size, void* d_ws, size_t ws_size,
                              hipStream_t stream) {
    const float* x = (const float*)d_in[0];
    float* out = (float*)d_out;
    dim3 grid(NC / TX, NR / TY, C);   // 32 x 32 x 6 = 6144 blocks
    dim3 block(256);
    s2_gaussian_blur_kernel<<<grid, block, 0, stream>>>(x, out);
}